// Round 9
// baseline (33.474 us; speedup 1.0000x reference)
//
#include <hip/hip_runtime.h>
#include <hip/hip_bf16.h>

// AWQ 4-bit linear: out[32,11008] = x[32,4096] @ ((q - z)*s) + bias
// Round 9: BARRIER-FREE main loop. Each wave stages its OWN 32-col x 32-k
// dequant tile in a private LDS region (no cross-wave sharing -> no
// __syncthreads -> no vmcnt(0) drain -> q-prefetch ring depth 3 actually
// stays in flight). Same verified fragment/swizzle math as rounds 4-8.
// KSPLIT=8, slab partials + reduce (no atomics).

#define IN_F   4096
#define OUT_F  11008
#define WCOLS  1376
#define NCOLB  86                 // 11008/128
#define KSPLIT 8
#define CHUNK  (IN_F/KSPLIT)      // 512
#define NTILE  (CHUNK/32)         // 16
#define NBLK   (NCOLB*KSPLIT)     // 688
#define MROWS  32
#define SLAB   (MROWS*OUT_F)      // floats per k-partial slab (352256)

typedef __attribute__((ext_vector_type(8))) short  short8;
typedef __attribute__((ext_vector_type(4))) short  short4v;
typedef __attribute__((ext_vector_type(4))) float  f32x4;
typedef __attribute__((ext_vector_type(4))) int    int4v;

__device__ __forceinline__ short f2bf(float f) {
  return (short)__builtin_bit_cast(unsigned short, (__bf16)f);
}
__device__ __forceinline__ f32x4 mfma16(short8 a, short8 b, f32x4 c) {
  return __builtin_amdgcn_mfma_f32_16x16x32_bf16(a, b, c, 0, 0, 0);
}

__global__ void awq_init(const float* __restrict__ bias, float* __restrict__ out) {
  int o = blockIdx.x * 256 + threadIdx.x;
  out[blockIdx.y * OUT_F + o] = bias[o];
}

__global__ void xconv(const float* __restrict__ x, unsigned short* __restrict__ xb) {
  int i = blockIdx.x * 256 + threadIdx.x;          // 128 blocks -> 32768 f32x4
  f32x4 v = ((const f32x4*)x)[i];
  short4v o;
  #pragma unroll
  for (int j = 0; j < 4; ++j) o[j] = f2bf(v[j]);
  ((short4v*)xb)[i] = o;
}

__global__ __launch_bounds__(256) void awq_reduce(
    const float* __restrict__ ws, const float* __restrict__ bias,
    float* __restrict__ out)
{
  const int i = blockIdx.x * 256 + threadIdx.x;    // f32x4 id, 88064 total
  const f32x4* w4 = (const f32x4*)ws;
  f32x4 s = w4[i];
  #pragma unroll
  for (int k = 1; k < KSPLIT; ++k) s += w4[k * (SLAB / 4) + i];
  const f32x4 b = *(const f32x4*)(bias + (i % (OUT_F / 4)) * 4);
  ((f32x4*)out)[i] = s + b;
}

template<bool PRE, bool TOWS>
__global__ __launch_bounds__(256, 3) void awq_main(
    const float* __restrict__ x, const unsigned short* __restrict__ xb,
    const int* __restrict__ qw, const int* __restrict__ qz,
    const float* __restrict__ sc, float* __restrict__ outp)
{
  // Per-wave private staging: [buf][wave][32 col][16 kp] dwords = 16 KB.
  __shared__ int lds[2][4][512];

  const int tid  = threadIdx.x;
  const int w    = tid >> 6;           // wave -> 32-col subtile
  const int lane = tid & 63;
  const int q4   = lane >> 4;
  const int ww   = lane & 3;           // word within wave's 4 -> cols 8ww..8ww+7
  const int kp2  = lane >> 2;          // k-pair 0..15 -> k = 2kp2, 2kp2+1

  // Bijective XCD swizzle (688 = 8*86)
  const int b  = blockIdx.x;
  const int L  = (b & 7) * (NBLK / 8) + (b >> 3);
  const int colblk = L % NCOLB;
  const int kchunk = L / NCOLB;

  const int cb  = colblk * 128;        // first output column
  const int wcb = colblk * 16;         // first packed word
  const int K0  = kchunk * CHUNK;
  const int g0  = kchunk * (CHUNK / 128);   // 4 groups per chunk
  const int wq  = wcb + 4 * w + ww;    // this lane's packed-word column

  // group scale/zero staging: raw (prefetched) -> converted s8/zs8
  f32x4 sra, srb; int zrw;
  float s8[8], zs8[8];
  auto load_group_raw = [&](int g) {
    sra = *(const f32x4*)(sc + g * OUT_F + cb + w * 32 + ww * 8);
    srb = *(const f32x4*)(sc + g * OUT_F + cb + w * 32 + ww * 8 + 4);
    zrw = qz[g * WCOLS + wq];
  };
  auto conv_group = [&]() {
    #pragma unroll
    for (int j = 0; j < 8; ++j) {
      const int sh = 4 * (j >> 1) + 16 * (j & 1);   // shift = 4*REV[j]
      const float sv = (j < 4) ? sra[j] : srb[j - 4];
      s8[j]  = sv;
      zs8[j] = -(float)((zrw >> sh) & 15) * sv;
    }
  };
  auto load_q = [&](int t, int& q0, int& q1) {
    const int r = (K0 + t * 32 + 2 * kp2) * WCOLS + wq;
    q0 = qw[r];
    q1 = qw[r + WCOLS];
  };
  auto load_a = [&](int t, int mf) -> short8 {
    const int m = (lane & 15) + 16 * mf;
    const int k = K0 + t * 32 + q4 * 8;
    if constexpr (PRE) {
      return *(const short8*)(xb + m * IN_F + k);
    } else {
      const f32x4* xp = (const f32x4*)(x + m * IN_F + k);
      f32x4 lo = xp[0], hi = xp[1];
      short8 af;
      #pragma unroll
      for (int j = 0; j < 4; ++j) { af[j] = f2bf(lo[j]); af[4 + j] = f2bf(hi[j]); }
      return af;
    }
  };
  // read element (col cl, kp=4q4+i): stored at cl*16 + (kp ^ ((cl>>3)<<2))
  // -> b128 at cl*16 + 4*(q4 ^ ((cl>>3)&3)) yields k-contiguous 8q4..8q4+7.
  auto read_b = [&](int p, int cl) -> short8 {
    const int idx = cl * 16 + 4 * (q4 ^ ((cl >> 3) & 3));
    return __builtin_bit_cast(short8, *(const int4v*)&lds[p][w][idx]);
  };

  // ---- prologue: group raws + q prefetch ring (depth 3, named regs)
  load_group_raw(g0);
  conv_group();
  int q0a, q1a, q0b, q1b, q0c, q1c;
  load_q(0, q0a, q1a);
  load_q(1, q0b, q1b);
  load_q(2, q0c, q1c);
  f32x4 acc[2][2] = {};

  #pragma unroll 4
  for (int t = 0; t < NTILE; ++t) {
    short8 a0 = load_a(t, 0), a1 = load_a(t, 1);
    int q0n = 0, q1n = 0;
    if (t + 3 < NTILE) load_q(t + 3, q0n, q1n);            // ring refill
    if ((t & 3) == 2 && (t >> 2) + 1 < CHUNK / 128)
      load_group_raw(g0 + (t >> 2) + 1);                   // raw 2 tiles early
    if ((t & 3) == 0 && t > 0) conv_group();

    // dequant 16 nibbles -> 8 packed bf16x2 -> private LDS (swizzled kp)
    const int p = t & 1;
    const int kps = kp2 ^ (ww << 2);
    #pragma unroll
    for (int j = 0; j < 8; ++j) {
      const int sh = 4 * (j >> 1) + 16 * (j & 1);
      const float lo = fmaf((float)((q0a >> sh) & 15), s8[j], zs8[j]);
      const float hi = fmaf((float)((q1a >> sh) & 15), s8[j], zs8[j]);
      const unsigned int pk =
          (unsigned int)(unsigned short)__builtin_bit_cast(unsigned short, (__bf16)lo) |
          ((unsigned int)(unsigned short)__builtin_bit_cast(unsigned short, (__bf16)hi) << 16);
      lds[p][w][(ww * 8 + j) * 16 + kps] = (int)pk;
    }
    // NO barrier: same-wave ds_write -> ds_read ordering via lgkmcnt only.

    const int cl = lane & 15;
    short8 bf0 = read_b(p, cl);
    short8 bf1 = read_b(p, cl + 16);

    acc[0][0] = mfma16(a0, bf0, acc[0][0]);
    acc[0][1] = mfma16(a0, bf1, acc[0][1]);
    acc[1][0] = mfma16(a1, bf0, acc[1][0]);
    acc[1][1] = mfma16(a1, bf1, acc[1][1]);

    // rotate prefetch ring (static, SSA-friendly)
    q0a = q0b; q1a = q1b;
    q0b = q0c; q1b = q1c;
    q0c = q0n; q1c = q1n;
  }

  // ---- epilogue
  const int col0 = cb + w * 32 + (lane & 15);
  const int r0 = q4 * 4;
  if constexpr (TOWS) {
    float* wsp = outp + kchunk * SLAB;
    #pragma unroll
    for (int mf = 0; mf < 2; ++mf) {
      #pragma unroll
      for (int i = 0; i < 4; ++i) {
        const int row = mf * 16 + r0 + i;
        wsp[row * OUT_F + col0]      = acc[mf][0][i];
        wsp[row * OUT_F + col0 + 16] = acc[mf][1][i];
      }
    }
  } else {
    #pragma unroll
    for (int mf = 0; mf < 2; ++mf) {
      #pragma unroll
      for (int i = 0; i < 4; ++i) {
        const int row = mf * 16 + r0 + i;
        atomicAdd(outp + row * OUT_F + col0,      acc[mf][0][i]);
        atomicAdd(outp + row * OUT_F + col0 + 16, acc[mf][1][i]);
      }
    }
  }
}

extern "C" void kernel_launch(void* const* d_in, const int* in_sizes, int n_in,
                              void* d_out, int out_size, void* d_ws, size_t ws_size,
                              hipStream_t stream) {
  const float* x    = (const float*)d_in[0];
  const int*   qwp  = (const int*)d_in[1];
  const int*   qzp  = (const int*)d_in[2];
  const float* scp  = (const float*)d_in[3];
  const float* bias = (const float*)d_in[4];
  float* out = (float*)d_out;

  const size_t ws_part = (size_t)KSPLIT * SLAB * sizeof(float);   // 11.25 MB
  const size_t xb_sz   = (size_t)MROWS * IN_F * 2;                // 256 KB

  if (ws_size >= ws_part + xb_sz) {
    float* ws = (float*)d_ws;
    unsigned short* xb = (unsigned short*)((char*)d_ws + ws_part);
    xconv<<<128, 256, 0, stream>>>(x, xb);
    awq_main<true, true><<<NBLK, 256, 0, stream>>>(x, xb, qwp, qzp, scp, ws);
    awq_reduce<<<SLAB / 4 / 256, 256, 0, stream>>>(ws, bias, out);
  } else {
    awq_init<<<dim3(43, 32), 256, 0, stream>>>(bias, out);
    awq_main<false, false><<<NBLK, 256, 0, stream>>>(x, nullptr, qwp, qzp, scp, out);
  }
}